// Round 12
// baseline (178.291 us; speedup 1.0000x reference)
//
#include <hip/hip_runtime.h>

typedef __attribute__((ext_vector_type(8))) short bf16x8;
typedef __attribute__((ext_vector_type(4))) float f32x4;

__device__ __forceinline__ float gelu_fast(float x) {
    const float u = 0.7978845608028654f * x * (1.0f + 0.044715f * x * x);
    return x * __builtin_amdgcn_rcpf(1.0f + __expf(-2.0f * u));
}

__device__ __forceinline__ unsigned short f2bf(float x) {
    union { float f; unsigned int u; } v; v.f = x;
    unsigned int r = v.u + 0x7FFF + ((v.u >> 16) & 1);
    return (unsigned short)(r >> 16);
}

// blocks [0,256): Gf production, parallel over (side, d-chunk, s-batch).
//   Gf[s][frag=nt*2+kk][lane][8] = Gc[s][e=(frag>>1)*16+(lane&15)][d=kk*32+(lane>>4)*8+j]
// blocks [256,260): weight transposes.
__global__ __launch_bounds__(256) void init_kernel(const float* __restrict__ phi_r, const float* __restrict__ mp_r,
                                                   const float* __restrict__ mm_r, unsigned short* __restrict__ GcR,
                                                   const float* __restrict__ phi_c, const float* __restrict__ mp_c,
                                                   const float* __restrict__ mm_c, unsigned short* __restrict__ GcC,
                                                   const float* __restrict__ w1r, const float* __restrict__ w1c,
                                                   const float* __restrict__ w2r, const float* __restrict__ w2c,
                                                   unsigned short* __restrict__ w1tr, unsigned short* __restrict__ w1tc,
                                                   unsigned short* __restrict__ w2tr, unsigned short* __restrict__ w2tc) {
    const int bid = blockIdx.x, tid = threadIdx.x;
    __shared__ float phis[256];
    __shared__ unsigned short tile[4096];  // 16 s x 256 (e-major, d-minor)
    if (bid < 256) {
        const int side = bid >> 7, rem = bid & 127;
        const int chunk = rem >> 3, s0 = (rem & 7) * 16;
        const float* phi = side ? phi_c : phi_r;
        const float* mp  = side ? mp_c  : mp_r;
        const float* mm  = side ? mm_c  : mm_r;
        unsigned short* Gct = side ? GcC : GcR;
        const int i = chunk * 256 + tid;
        float pe[16], po[16];
#pragma unroll
        for (int k = 0; k < 16; ++k) {
            const float a = mp[k * 4096 + i];
            const float b = mm[k * 4096 + i];
            pe[k] = a + b; po[k] = a - b;
        }
        phis[tid] = phi[s0 * 16 + tid];
        __syncthreads();
        const int e = tid & 63, dl = tid >> 6;
        const int d0 = chunk * 4;
        const int kk = d0 >> 5, g3 = (d0 >> 3) & 3, jl0 = d0 & 7;
#pragma unroll
        for (int sb = 0; sb < 16; ++sb) {
            const int s = s0 + sb;
            const float* pk = &phis[sb * 16];
            float acc = 0.0f;
            if (s & 1) {
#pragma unroll
                for (int k = 0; k < 16; ++k) acc += pk[k] * po[k];
            } else {
#pragma unroll
                for (int k = 0; k < 16; ++k) acc += pk[k] * pe[k];
            }
            tile[sb * 256 + e * 4 + dl] = f2bf(acc);
        }
        __syncthreads();
#pragma unroll
        for (int it = 0; it < 4; ++it) {
            const int p = it * 256 + tid;
            const int sb = p >> 6, ee = p & 63;
            uint2 v = *(const uint2*)&tile[sb * 256 + ee * 4];
            *(uint2*)&Gct[(size_t)(s0 + sb) * 4096 + (((ee >> 4) << 1) + kk) * 512 +
                          (g3 * 16 + (ee & 15)) * 8 + jl0] = v;
        }
    } else {
        const int b = bid - 256;
        if (b < 2) {
            const float* w1 = b ? w1c : w1r;
            unsigned short* dst = b ? w1tc : w1tr;
            const int n = tid;
            for (int k = 0; k < 64; ++k) dst[n * 64 + k] = f2bf(w1[k * 256 + n]);
        } else {
            const float* w2 = (b == 3) ? w2c : w2r;
            unsigned short* dst = (b == 3) ? w2tc : w2tr;
            const int n = tid & 63, kq = tid >> 6;
            for (int kk2 = 0; kk2 < 64; ++kk2) {
                const int k = kq * 64 + kk2;
                dst[n * 256 + k] = f2bf(w2[k * 64 + n]);
            }
        }
    }
}

// Row-split fused pass. TYPE 0: output rows 0-63 (needs s<64, t<64).
// TYPE 1: output rows 64-127 (all s, all t). 2 blocks per seq, grid 1024.
// 4 waves, acc[4][4] (64 AGPR), single-buffered B regs, 50 KB LDS -> target 3 blocks/CU.
// LDS bytes: ys [0, YROWS*128); scrA [18432,34816) scrB [34816,51200);
//            X [0,8192) (after spec); H-half [8192,24576).
template<int TYPE>
__device__ __forceinline__ void fused_body(int seq, int tid,
                                           const float* __restrict__ xin, float* __restrict__ xout,
                                           const unsigned short* __restrict__ Gf,
                                           const unsigned short* __restrict__ w1t,
                                           const unsigned short* __restrict__ w2t,
                                           const float* __restrict__ b1, const float* __restrict__ b2,
                                           const float* __restrict__ gamma, const float* __restrict__ beta,
                                           int rmul, int tmul, unsigned short* lds) {
    constexpr int J0 = TYPE ? 4 : 0;     // first j-tile
    constexpr int SN = TYPE ? 128 : 64;  // s (and t) range
    constexpr int SR = SN / 4;           // rounds
    constexpr int R0 = TYPE ? 64 : 0;    // first output row
    const int w = tid >> 6, lane = tid & 63;
    const int m = lane & 15, g = lane >> 4;
    const int bb = seq >> 7, rr = seq & 127;
    const size_t base = (size_t)bb * 1048576 + (size_t)rr * (size_t)rmul;

    // zero ys prefix rows 0..15
    { uint2 z; z.x = 0u; z.y = 0u; *(uint2*)((char*)lds + tid * 8) = z; }

    // ---- LN rows t in [0, SN), wave w handles SN/4 rows in 16-row batches ----
    {
        const float gl = gamma[lane], bl = beta[lane];
#pragma unroll
        for (int batch = 0; batch < SN / 64; ++batch) {
            float xv[16];
            const int t0 = w * (SN / 4) + batch * 16;
#pragma unroll
            for (int ti = 0; ti < 16; ++ti)
                xv[ti] = xin[base + (size_t)(t0 + ti) * tmul + lane];
#pragma unroll
            for (int ti = 0; ti < 16; ++ti) {
                const int t = t0 + ti;
                float s1 = xv[ti];
#pragma unroll
                for (int mk = 32; mk >= 1; mk >>= 1) s1 += __shfl_xor(s1, mk);
                const float mu = s1 * (1.0f / 64.0f);
                const float dv = xv[ti] - mu;
                float s2 = dv * dv;
#pragma unroll
                for (int mk = 32; mk >= 1; mk >>= 1) s2 += __shfl_xor(s2, mk);
                const float rstd = rsqrtf(s2 * (1.0f / 64.0f) + 1e-5f);
                const float nv = dv * rstd * gl + bl;
                lds[(t + 16) * 64 + (((lane >> 3) ^ (t & 7)) << 3) + (lane & 7)] = f2bf(nv);
            }
        }
    }
    __syncthreads();  // ys ready

    // ---- spec: rounds over s = 4r+w; tiles jt -> global j = J0+jt ----
    f32x4 acc[4][4];
#pragma unroll
    for (int jt = 0; jt < 4; ++jt)
#pragma unroll
        for (int nt = 0; nt < 4; ++nt) {
            f32x4 z = {0.0f, 0.0f, 0.0f, 0.0f};
            acc[jt][nt] = z;
        }
    for (int r = 0; r < SR; ++r) {
        const int s = 4 * r + w;
        bf16x8 Ba[8];
        {
            const unsigned short* gq = Gf + (size_t)s * 4096 + lane * 8;
#pragma unroll
            for (int f = 0; f < 8; ++f) Ba[f] = *(const bf16x8*)(gq + f * 512);
        }
        int jmin = (s >> 4) - J0; if (jmin < 0) jmin = 0;
        jmin = __builtin_amdgcn_readfirstlane(jmin);
#pragma unroll
        for (int jt = 0; jt < 4; ++jt) {
            if (jt >= jmin) {
                const int row_ = 16 + 16 * (J0 + jt) - s + m;
                const int c0 = (g ^ (row_ & 7)) << 3;
                bf16x8 a0 = *(const bf16x8*)&lds[row_ * 64 + c0];
                bf16x8 a1 = *(const bf16x8*)&lds[row_ * 64 + (c0 ^ 32)];
#pragma unroll
                for (int nt = 0; nt < 4; ++nt) {
                    acc[jt][nt] = __builtin_amdgcn_mfma_f32_16x16x32_bf16(a0, Ba[2 * nt], acc[jt][nt], 0, 0, 0);
                    acc[jt][nt] = __builtin_amdgcn_mfma_f32_16x16x32_bf16(a1, Ba[2 * nt + 1], acc[jt][nt], 0, 0, 0);
                }
            }
        }
    }

    // ---- reduction over the 4 s-residues (full-acc dumps, 3 barriers) ----
    char* const scrA = (char*)lds + 18432;
    char* const scrB = (char*)lds + 34816;
    if (w == 1 || w == 3) {
        char* pb = (w == 1 ? scrA : scrB) + lane * 16;
#pragma unroll
        for (int jt = 0; jt < 4; ++jt)
#pragma unroll
            for (int nt = 0; nt < 4; ++nt)
                *(f32x4*)(pb + (jt * 4 + nt) * 1024) = acc[jt][nt];
    }
    // weight fragments (overlap reduction); wave owns hidden cols [32w,32w+32) per half
    bf16x8 bw1a[2][2], bw1b[2][2];
    float b1va[2], b1vb[2];
#pragma unroll
    for (int nt = 0; nt < 2; ++nt) {
        const int col0 = w * 32 + nt * 16 + m;
#pragma unroll
        for (int j = 0; j < 2; ++j) {
            bw1a[nt][j] = *(const bf16x8*)&w1t[col0 * 64 + (4 * j + g) * 8];
            bw1b[nt][j] = *(const bf16x8*)&w1t[(128 + col0) * 64 + (4 * j + g) * 8];
        }
        b1va[nt] = b1[col0];
        b1vb[nt] = b1[128 + col0];
    }
    __syncthreads();
    if (w == 0 || w == 2) {
        const char* pb = (w == 0 ? scrA : scrB) + lane * 16;
#pragma unroll
        for (int jt = 0; jt < 4; ++jt)
#pragma unroll
            for (int nt = 0; nt < 4; ++nt)
                acc[jt][nt] += *(const f32x4*)(pb + (jt * 4 + nt) * 1024);
    }
    __syncthreads();
    if (w == 2) {
        char* pb = scrA + lane * 16;
#pragma unroll
        for (int jt = 0; jt < 4; ++jt)
#pragma unroll
            for (int nt = 0; nt < 4; ++nt)
                *(f32x4*)(pb + (jt * 4 + nt) * 1024) = acc[jt][nt];
    }
    __syncthreads();
    if (w == 0) {  // full sum -> X bf16 (local rows 0..63) at [0,8192)
#pragma unroll
        for (int jt = 0; jt < 4; ++jt)
#pragma unroll
            for (int nt = 0; nt < 4; ++nt) {
                acc[jt][nt] += *(const f32x4*)(scrA + (jt * 4 + nt) * 1024 + lane * 16);
#pragma unroll
                for (int rv = 0; rv < 4; ++rv) {
                    const int row = jt * 16 + 4 * g + rv;
                    const int col = nt * 16 + m;
                    lds[row * 64 + (((col >> 3) ^ (row & 7)) << 3) + (col & 7)] = f2bf(acc[jt][nt][rv]);
                }
            }
    }
    __syncthreads();  // X ready; scratch dead

    // ---- MLP (64 rows) in two hidden halves; H at ush 4096, row stride 128 ----
    float b2v[4];
#pragma unroll
    for (int nt = 0; nt < 4; ++nt) b2v[nt] = b2[nt * 16 + m];
    f32x4 acc2[4];
#pragma unroll
    for (int nt = 0; nt < 4; ++nt) {
        f32x4 z = {b2v[nt], b2v[nt], b2v[nt], b2v[nt]};
        acc2[nt] = z;
    }
#pragma unroll
    for (int half = 0; half < 2; ++half) {
        f32x4 acc1[4][2];
#pragma unroll
        for (int mt = 0; mt < 4; ++mt)
#pragma unroll
            for (int nt = 0; nt < 2; ++nt) {
                const float bv = half ? b1vb[nt] : b1va[nt];
                f32x4 z = {bv, bv, bv, bv};
                acc1[mt][nt] = z;
            }
#pragma unroll
        for (int mt = 0; mt < 4; ++mt) {
            const int row = mt * 16 + m;
            const int c0 = (g ^ (row & 7)) << 3;
            bf16x8 a0 = *(const bf16x8*)&lds[row * 64 + c0];
            bf16x8 a1 = *(const bf16x8*)&lds[row * 64 + (c0 ^ 32)];
#pragma unroll
            for (int nt = 0; nt < 2; ++nt) {
                const bf16x8 w0f = half ? bw1b[nt][0] : bw1a[nt][0];
                const bf16x8 w1f = half ? bw1b[nt][1] : bw1a[nt][1];
                acc1[mt][nt] = __builtin_amdgcn_mfma_f32_16x16x32_bf16(a0, w0f, acc1[mt][nt], 0, 0, 0);
                acc1[mt][nt] = __builtin_amdgcn_mfma_f32_16x16x32_bf16(a1, w1f, acc1[mt][nt], 0, 0, 0);
            }
        }
#pragma unroll
        for (int mt = 0; mt < 4; ++mt)
#pragma unroll
            for (int nt = 0; nt < 2; ++nt) {
                const int col = w * 32 + nt * 16 + m;
                const int c = col >> 3, jj = col & 7;
#pragma unroll
                for (int rv = 0; rv < 4; ++rv) {
                    const int row = mt * 16 + 4 * g + rv;
                    lds[4096 + row * 128 + ((c ^ (row & 7)) << 3) + jj] = f2bf(gelu_fast(acc1[mt][nt][rv]));
                }
            }
        __syncthreads();  // H half ready

        const int arow = w * 16 + m;  // this wave's m-tile rows
#pragma unroll
        for (int jj = 0; jj < 4; ++jj) {
            bf16x8 aa = *(const bf16x8*)&lds[4096 + arow * 128 + (((4 * jj + g) ^ (arow & 7)) << 3)];
#pragma unroll
            for (int nt = 0; nt < 4; ++nt) {
                const bf16x8 bfr = *(const bf16x8*)&w2t[(nt * 16 + m) * 256 + half * 128 + (4 * jj + g) * 8];
                acc2[nt] = __builtin_amdgcn_mfma_f32_16x16x32_bf16(aa, bfr, acc2[nt], 0, 0, 0);
            }
        }
        if (half == 0) __syncthreads();  // H reused by half 1
    }

    // ---- residual + store: rows R0 + w*16 + 4g+rv ----
#pragma unroll
    for (int nt = 0; nt < 4; ++nt)
#pragma unroll
        for (int rv = 0; rv < 4; ++rv) {
            const int row = R0 + w * 16 + 4 * g + rv;
            const int col = nt * 16 + m;
            const size_t xi = base + (size_t)row * tmul + col;
            xout[xi] = xin[xi] + acc2[nt][rv];
        }
}

// NOTE: __launch_bounds__ min-waves stays at 2 — (256,3) forced VGPR<=~85 in R10 and
// spilled MFMA accumulators (600 MB scratch, 3.8x slower). Occupancy comes from the
// smaller acc[4][4] + single-buffer B register footprint + 50 KB LDS.
__global__ __launch_bounds__(256, 2) void fused_kernel(const float* __restrict__ xin,
                                                       float* __restrict__ xout,
                                                       const unsigned short* __restrict__ Gf,
                                                       const unsigned short* __restrict__ w1t,
                                                       const unsigned short* __restrict__ w2t,
                                                       const float* __restrict__ b1,
                                                       const float* __restrict__ b2,
                                                       const float* __restrict__ gamma,
                                                       const float* __restrict__ beta,
                                                       int rmul, int tmul) {
    __shared__ unsigned short lds[25600];  // 50 KB
    const int bid = blockIdx.x, tid = threadIdx.x;
    const int seq = bid >> 1;
    if (bid & 1)
        fused_body<1>(seq, tid, xin, xout, Gf, w1t, w2t, b1, b2, gamma, beta, rmul, tmul, lds);
    else
        fused_body<0>(seq, tid, xin, xout, Gf, w1t, w2t, b1, b2, gamma, beta, rmul, tmul, lds);
}

extern "C" void kernel_launch(void* const* d_in, const int* in_sizes, int n_in,
                              void* d_out, int out_size, void* d_ws, size_t ws_size,
                              hipStream_t stream) {
    const float* v         = (const float*)d_in[0];
    const float* gamma_row = (const float*)d_in[1];
    const float* beta_row  = (const float*)d_in[2];
    const float* gamma_col = (const float*)d_in[3];
    const float* beta_col  = (const float*)d_in[4];
    const float* mp_row    = (const float*)d_in[5];
    const float* mm_row    = (const float*)d_in[6];
    const float* mp_col    = (const float*)d_in[7];
    const float* mm_col    = (const float*)d_in[8];
    const float* w1_row    = (const float*)d_in[9];
    const float* b1_row    = (const float*)d_in[10];
    const float* w2_row    = (const float*)d_in[11];
    const float* b2_row    = (const float*)d_in[12];
    const float* w1_col    = (const float*)d_in[13];
    const float* b1_col    = (const float*)d_in[14];
    const float* w2_col    = (const float*)d_in[15];
    const float* b2_col    = (const float*)d_in[16];
    const float* phi_row   = (const float*)d_in[17];
    const float* phi_col   = (const float*)d_in[18];
    float* out = (float*)d_out;
    char* ws   = (char*)d_ws;

    unsigned short* GfR  = (unsigned short*)ws;                      // 1 MB
    unsigned short* GfC  = (unsigned short*)(ws + (1u << 20));       // 1 MB
    unsigned short* w1tR = (unsigned short*)(ws + (2u << 20));
    unsigned short* w2tR = (unsigned short*)(ws + (2u << 20) + 32768);
    unsigned short* w1tC = (unsigned short*)(ws + (2u << 20) + 65536);
    unsigned short* w2tC = (unsigned short*)(ws + (2u << 20) + 98304);

    init_kernel<<<260, 256, 0, stream>>>(phi_row, mp_row, mm_row, GfR,
                                         phi_col, mp_col, mm_col, GfC,
                                         w1_row, w1_col, w2_row, w2_col,
                                         w1tR, w1tC, w2tR, w2tC);

    // row pass: seq=(b,h), rmul=8192 (h stride), tmul=64 (w stride)
    fused_kernel<<<1024, 256, 0, stream>>>(v, out, GfR, w1tR, w2tR, b1_row, b2_row,
                                           gamma_row, beta_row, 8192, 64);
    // col pass: seq=(b,w), rmul=64 (w stride), tmul=8192 (h stride)
    fused_kernel<<<1024, 256, 0, stream>>>(out, out, GfC, w1tC, w2tC, b1_col, b2_col,
                                           gamma_col, beta_col, 64, 8192);
}

// Round 13
// 144.014 us; speedup vs baseline: 1.2380x; 1.2380x over previous
//
#include <hip/hip_runtime.h>

typedef __attribute__((ext_vector_type(8))) short bf16x8;
typedef __attribute__((ext_vector_type(4))) float f32x4;

__device__ __forceinline__ float gelu_fast(float x) {
    const float u = 0.7978845608028654f * x * (1.0f + 0.044715f * x * x);
    return x * __builtin_amdgcn_rcpf(1.0f + __expf(-2.0f * u));
}

__device__ __forceinline__ unsigned short f2bf(float x) {
    union { float f; unsigned int u; } v; v.f = x;
    unsigned int r = v.u + 0x7FFF + ((v.u >> 16) & 1);
    return (unsigned short)(r >> 16);
}

// blocks [0,256): Gf production, parallel over (side, d-chunk, s-batch).
//   Gf[s][frag=nt*2+kk][lane][8] = Gc[s][e=(frag>>1)*16+(lane&15)][d=kk*32+(lane>>4)*8+j]
// blocks [256,260): weight transposes.
__global__ __launch_bounds__(256) void init_kernel(const float* __restrict__ phi_r, const float* __restrict__ mp_r,
                                                   const float* __restrict__ mm_r, unsigned short* __restrict__ GcR,
                                                   const float* __restrict__ phi_c, const float* __restrict__ mp_c,
                                                   const float* __restrict__ mm_c, unsigned short* __restrict__ GcC,
                                                   const float* __restrict__ w1r, const float* __restrict__ w1c,
                                                   const float* __restrict__ w2r, const float* __restrict__ w2c,
                                                   unsigned short* __restrict__ w1tr, unsigned short* __restrict__ w1tc,
                                                   unsigned short* __restrict__ w2tr, unsigned short* __restrict__ w2tc) {
    const int bid = blockIdx.x, tid = threadIdx.x;
    __shared__ float phis[256];
    __shared__ unsigned short tile[4096];  // 16 s x 256 (e-major, d-minor)
    if (bid < 256) {
        const int side = bid >> 7, rem = bid & 127;
        const int chunk = rem >> 3, s0 = (rem & 7) * 16;
        const float* phi = side ? phi_c : phi_r;
        const float* mp  = side ? mp_c  : mp_r;
        const float* mm  = side ? mm_c  : mm_r;
        unsigned short* Gct = side ? GcC : GcR;
        const int i = chunk * 256 + tid;
        float pe[16], po[16];
#pragma unroll
        for (int k = 0; k < 16; ++k) {
            const float a = mp[k * 4096 + i];
            const float b = mm[k * 4096 + i];
            pe[k] = a + b; po[k] = a - b;
        }
        phis[tid] = phi[s0 * 16 + tid];
        __syncthreads();
        const int e = tid & 63, dl = tid >> 6;
        const int d0 = chunk * 4;
        const int kk = d0 >> 5, g3 = (d0 >> 3) & 3, jl0 = d0 & 7;
#pragma unroll
        for (int sb = 0; sb < 16; ++sb) {
            const int s = s0 + sb;
            const float* pk = &phis[sb * 16];
            float acc = 0.0f;
            if (s & 1) {
#pragma unroll
                for (int k = 0; k < 16; ++k) acc += pk[k] * po[k];
            } else {
#pragma unroll
                for (int k = 0; k < 16; ++k) acc += pk[k] * pe[k];
            }
            tile[sb * 256 + e * 4 + dl] = f2bf(acc);
        }
        __syncthreads();
#pragma unroll
        for (int it = 0; it < 4; ++it) {
            const int p = it * 256 + tid;
            const int sb = p >> 6, ee = p & 63;
            uint2 v = *(const uint2*)&tile[sb * 256 + ee * 4];
            *(uint2*)&Gct[(size_t)(s0 + sb) * 4096 + (((ee >> 4) << 1) + kk) * 512 +
                          (g3 * 16 + (ee & 15)) * 8 + jl0] = v;
        }
    } else {
        const int b = bid - 256;
        if (b < 2) {
            const float* w1 = b ? w1c : w1r;
            unsigned short* dst = b ? w1tc : w1tr;
            const int n = tid;
            for (int k = 0; k < 64; ++k) dst[n * 64 + k] = f2bf(w1[k * 256 + n]);
        } else {
            const float* w2 = (b == 3) ? w2c : w2r;
            unsigned short* dst = (b == 3) ? w2tc : w2tr;
            const int n = tid & 63, kq = tid >> 6;
            for (int kk2 = 0; kk2 < 64; ++kk2) {
                const int k = kq * 64 + kk2;
                dst[n * 256 + k] = f2bf(w2[k * 64 + n]);
            }
        }
    }
}

// Fused pass: LN -> spec (reg-streaming B, double-buffered, no main-loop barriers)
// -> tree-reduce -> MLP(2 halves) -> residual (register-prefetched).
// 1 seq/block, 4 waves, grid 512 (2 blocks/CU). 50 KB LDS.
// REGISTER BUDGET (unified file, 2 waves/SIMD => 256/wave): spec-phase peak =
// acc[8][4](128) + Ba/Bb(64) + ~60 misc = ~252. DO NOT add spec-phase registers
// (3-deep prefetch spills). Post-spec has ~45 regs free -> residual prefetch only.
// NOTE: __launch_bounds__ min-waves MUST stay 2 — (256,3) caps regs at ~85 and
// spills accumulators (R10: 600 MB scratch, 3.8x slower).
// LDS byte regions (time-shared):
//   ys      [0, 18432)                 LN + spec loop
//   scrA    [18432, 34816), scrB [34816, 51200)   reduction (16 KB each)
//   X       [0, 16384)                 after reduction (overwrites ys)
//   H half  [16384, 49152)             GEMM1 out (32 KB; overwrites scrA/B)
#define SPEC_BODY(RR, BC, BN)                                                        \
    {                                                                                \
        const int s_ = 4 * (RR) + w;                                                 \
        if ((RR) < 31) {                                                             \
            const unsigned short* gq = Gf + (size_t)(s_ + 4) * 4096 + lane * 8;      \
            _Pragma("unroll")                                                        \
            for (int f = 0; f < 8; ++f) BN[f] = *(const bf16x8*)(gq + f * 512);      \
        }                                                                            \
        const int jmin_ = __builtin_amdgcn_readfirstlane(s_ >> 4);                   \
        _Pragma("unroll")                                                            \
        for (int j = 0; j < 8; ++j) {                                                \
            if (j >= jmin_) {                                                        \
                const int row_ = 16 + 16 * j - s_ + m;                               \
                const int c0_ = (g ^ (row_ & 7)) << 3;                               \
                const int ab_ = row_ * 64;                                           \
                bf16x8 a0_ = *(const bf16x8*)&lds[ab_ + c0_];                        \
                bf16x8 a1_ = *(const bf16x8*)&lds[ab_ + (c0_ ^ 32)];                 \
                _Pragma("unroll")                                                    \
                for (int nt = 0; nt < 4; ++nt) {                                     \
                    acc[j][nt] = __builtin_amdgcn_mfma_f32_16x16x32_bf16(a0_, BC[2 * nt], acc[j][nt], 0, 0, 0);     \
                    acc[j][nt] = __builtin_amdgcn_mfma_f32_16x16x32_bf16(a1_, BC[2 * nt + 1], acc[j][nt], 0, 0, 0); \
                }                                                                    \
            }                                                                        \
        }                                                                            \
    }

__global__ __launch_bounds__(256, 2) void fused_kernel(const float* __restrict__ xin,
                                                       float* __restrict__ xout,
                                                       const unsigned short* __restrict__ Gf,
                                                       const unsigned short* __restrict__ w1t,
                                                       const unsigned short* __restrict__ w2t,
                                                       const float* __restrict__ b1,
                                                       const float* __restrict__ b2,
                                                       const float* __restrict__ gamma,
                                                       const float* __restrict__ beta,
                                                       int rmul, int tmul) {
    __shared__ unsigned short lds[25600];  // 50 KB
    const int tid = threadIdx.x;
    const int w = tid >> 6, lane = tid & 63;
    const int seq = blockIdx.x;
    const int m = lane & 15, g = lane >> 4;
    const int bb = seq >> 7, rr = seq & 127;
    const size_t base = (size_t)bb * 1048576 + (size_t)rr * (size_t)rmul;

    // zero ys prefix rows 0..15 (bytes [0,2048))
    {
        uint2 z; z.x = 0u; z.y = 0u;
        *(uint2*)((char*)lds + tid * 8) = z;
    }

    // issue spec round-0 B load early (hides L2 latency under LN)
    bf16x8 Ba[8], Bb[8];
    {
        const unsigned short* gq = Gf + (size_t)w * 4096 + lane * 8;
#pragma unroll
        for (int f = 0; f < 8; ++f) Ba[f] = *(const bf16x8*)(gq + f * 512);
    }

    // ---- Phase 0: LayerNorm rows w*32 .. w*32+31 into swizzled ys ----
    {
        const float gl = gamma[lane], bl = beta[lane];
        float xv[32];
#pragma unroll
        for (int ti = 0; ti < 32; ++ti)
            xv[ti] = xin[base + (size_t)(w * 32 + ti) * tmul + lane];
#pragma unroll
        for (int ti = 0; ti < 32; ++ti) {
            const int t = w * 32 + ti;
            float s1 = xv[ti];
#pragma unroll
            for (int mm2 = 32; mm2 >= 1; mm2 >>= 1) s1 += __shfl_xor(s1, mm2);
            const float mu = s1 * (1.0f / 64.0f);
            const float dv = xv[ti] - mu;
            float s2 = dv * dv;
#pragma unroll
            for (int mm2 = 32; mm2 >= 1; mm2 >>= 1) s2 += __shfl_xor(s2, mm2);
            const float rstd = rsqrtf(s2 * (1.0f / 64.0f) + 1e-5f);
            const float nv = dv * rstd * gl + bl;
            lds[(t + 16) * 64 + (((lane >> 3) ^ (t & 7)) << 3) + (lane & 7)] = f2bf(nv);
        }
    }
    __syncthreads();  // ys complete

    // ---- Phase 1: spec main loop (no barriers) ----
    f32x4 acc[8][4];
#pragma unroll
    for (int j = 0; j < 8; ++j)
#pragma unroll
        for (int nt = 0; nt < 4; ++nt) {
            f32x4 z = {0.0f, 0.0f, 0.0f, 0.0f};
            acc[j][nt] = z;
        }
    for (int rp = 0; rp < 16; ++rp) {
        SPEC_BODY(2 * rp,     Ba, Bb);
        SPEC_BODY(2 * rp + 1, Bb, Ba);
    }

    // ---- Phase 2: pairwise tree reduction (32 KB scratch) ----
    char* const scrA = (char*)lds + 18432;
    char* const scrB = (char*)lds + 34816;
    // T1: w1 -> scrA (j0-3), w3 -> scrB (j0-3)
    if (w == 1 || w == 3) {
        char* pb = (w == 1 ? scrA : scrB) + lane * 16;
#pragma unroll
        for (int j = 0; j < 4; ++j)
#pragma unroll
            for (int nt = 0; nt < 4; ++nt)
                *(f32x4*)(pb + (j * 4 + nt) * 1024) = acc[j][nt];
    }
    // residual prefetch (global, consumed at final store; overlaps reduction barriers)
    float xr[2][4][4];
#pragma unroll
    for (int mt = 0; mt < 2; ++mt)
#pragma unroll
        for (int nt = 0; nt < 4; ++nt)
#pragma unroll
            for (int rv = 0; rv < 4; ++rv)
                xr[mt][nt][rv] = xin[base + (size_t)((w + 4 * mt) * 16 + 4 * g + rv) * tmul + nt * 16 + m];
    // weight fragment loads (overlap reduction); wave owns hidden cols [32w,32w+32) per half
    bf16x8 bw1a[2][2], bw1b[2][2];
    float b1va[2], b1vb[2];
#pragma unroll
    for (int nt = 0; nt < 2; ++nt) {
        const int col0 = w * 32 + nt * 16 + m;
#pragma unroll
        for (int j = 0; j < 2; ++j) {
            bw1a[nt][j] = *(const bf16x8*)&w1t[col0 * 64 + (4 * j + g) * 8];
            bw1b[nt][j] = *(const bf16x8*)&w1t[(128 + col0) * 64 + (4 * j + g) * 8];
        }
        b1va[nt] = b1[col0];
        b1vb[nt] = b1[128 + col0];
    }
    __syncthreads();
    // T2: w0 += scrA, w2 += scrB (j0-3)
    if (w == 0 || w == 2) {
        const char* pb = (w == 0 ? scrA : scrB) + lane * 16;
#pragma unroll
        for (int j = 0; j < 4; ++j)
#pragma unroll
            for (int nt = 0; nt < 4; ++nt)
                acc[j][nt] += *(const f32x4*)(pb + (j * 4 + nt) * 1024);
    }
    __syncthreads();
    // T3: w1 -> scrA (j4-7), w3 -> scrB (j4-7)
    if (w == 1 || w == 3) {
        char* pb = (w == 1 ? scrA : scrB) + lane * 16;
#pragma unroll
        for (int j = 4; j < 8; ++j)
#pragma unroll
            for (int nt = 0; nt < 4; ++nt)
                *(f32x4*)(pb + ((j - 4) * 4 + nt) * 1024) = acc[j][nt];
    }
    __syncthreads();
    // T4: w0 += scrA, w2 += scrB (j4-7); then T5: w0 -> scrA (j4-7), w2 -> scrB (j0-3)
    if (w == 0 || w == 2) {
        const char* pb = (w == 0 ? scrA : scrB) + lane * 16;
#pragma unroll
        for (int j = 4; j < 8; ++j)
#pragma unroll
            for (int nt = 0; nt < 4; ++nt)
                acc[j][nt] += *(const f32x4*)(pb + ((j - 4) * 4 + nt) * 1024);
        if (w == 0) {
#pragma unroll
            for (int j = 4; j < 8; ++j)
#pragma unroll
                for (int nt = 0; nt < 4; ++nt)
                    *(f32x4*)(scrA + ((j - 4) * 4 + nt) * 1024 + lane * 16) = acc[j][nt];
        } else {
#pragma unroll
            for (int j = 0; j < 4; ++j)
#pragma unroll
                for (int nt = 0; nt < 4; ++nt)
                    *(f32x4*)(scrB + (j * 4 + nt) * 1024 + lane * 16) = acc[j][nt];
        }
    }
    __syncthreads();
    // T6: w0 finalizes j0-3 -> X rows 0..63; w2 finalizes j4-7 -> X rows 64..127
    if (w == 0) {
#pragma unroll
        for (int j = 0; j < 4; ++j)
#pragma unroll
            for (int nt = 0; nt < 4; ++nt) {
                acc[j][nt] += *(const f32x4*)(scrB + (j * 4 + nt) * 1024 + lane * 16);
#pragma unroll
                for (int rv = 0; rv < 4; ++rv) {
                    const int row = j * 16 + 4 * g + rv;
                    const int col = nt * 16 + m;
                    lds[row * 64 + (((col >> 3) ^ (row & 7)) << 3) + (col & 7)] = f2bf(acc[j][nt][rv]);
                }
            }
    } else if (w == 2) {
#pragma unroll
        for (int j = 4; j < 8; ++j)
#pragma unroll
            for (int nt = 0; nt < 4; ++nt) {
                acc[j][nt] += *(const f32x4*)(scrA + ((j - 4) * 4 + nt) * 1024 + lane * 16);
#pragma unroll
                for (int rv = 0; rv < 4; ++rv) {
                    const int row = j * 16 + 4 * g + rv;
                    const int col = nt * 16 + m;
                    lds[row * 64 + (((col >> 3) ^ (row & 7)) << 3) + (col & 7)] = f2bf(acc[j][nt][rv]);
                }
            }
    }
    __syncthreads();  // X complete; scratch dead

    // ---- Phase 3/4: MLP in two 128-col hidden halves; H at ush offset 8192, row stride 128 ush ----
    float b2v[4];
#pragma unroll
    for (int nt = 0; nt < 4; ++nt) b2v[nt] = b2[nt * 16 + m];
    f32x4 acc2[2][4];
#pragma unroll
    for (int mt = 0; mt < 2; ++mt)
#pragma unroll
        for (int nt = 0; nt < 4; ++nt) {
            f32x4 z = {b2v[nt], b2v[nt], b2v[nt], b2v[nt]};
            acc2[mt][nt] = z;
        }

#pragma unroll
    for (int half = 0; half < 2; ++half) {
        // GEMM1 half: H[:, 128*half + 32w .. +32) = gelu(X @ W1half + b1half)
        f32x4 acc1[8][2];
#pragma unroll
        for (int mt = 0; mt < 8; ++mt)
#pragma unroll
            for (int nt = 0; nt < 2; ++nt) {
                const float bv = half ? b1vb[nt] : b1va[nt];
                f32x4 z = {bv, bv, bv, bv};
                acc1[mt][nt] = z;
            }
#pragma unroll
        for (int mt = 0; mt < 8; ++mt) {
            const int row = mt * 16 + m;
            const int c0 = (g ^ (row & 7)) << 3;
            bf16x8 a0 = *(const bf16x8*)&lds[row * 64 + c0];
            bf16x8 a1 = *(const bf16x8*)&lds[row * 64 + (c0 ^ 32)];
#pragma unroll
            for (int nt = 0; nt < 2; ++nt) {
                const bf16x8 w0f = half ? bw1b[nt][0] : bw1a[nt][0];
                const bf16x8 w1f = half ? bw1b[nt][1] : bw1a[nt][1];
                acc1[mt][nt] = __builtin_amdgcn_mfma_f32_16x16x32_bf16(a0, w0f, acc1[mt][nt], 0, 0, 0);
                acc1[mt][nt] = __builtin_amdgcn_mfma_f32_16x16x32_bf16(a1, w1f, acc1[mt][nt], 0, 0, 0);
            }
        }
        // gelu + H half to LDS (cols within half: 32w + nt*16 + m)
#pragma unroll
        for (int mt = 0; mt < 8; ++mt)
#pragma unroll
            for (int nt = 0; nt < 2; ++nt) {
                const int col = w * 32 + nt * 16 + m;
                const int c = col >> 3, jj = col & 7;
#pragma unroll
                for (int rv = 0; rv < 4; ++rv) {
                    const int row = mt * 16 + 4 * g + rv;
                    lds[8192 + row * 128 + ((c ^ (row & 7)) << 3) + jj] = f2bf(gelu_fast(acc1[mt][nt][rv]));
                }
            }
        __syncthreads();  // H half complete

        // GEMM2 partial: K chunk [128*half, 128*half+128)
#pragma unroll
        for (int j = 0; j < 4; ++j) {
            bf16x8 aa[2];
#pragma unroll
            for (int mt = 0; mt < 2; ++mt) {
                const int row = (w + 4 * mt) * 16 + m;
                aa[mt] = *(const bf16x8*)&lds[8192 + row * 128 + (((4 * j + g) ^ (row & 7)) << 3)];
            }
#pragma unroll
            for (int nt = 0; nt < 4; ++nt) {
                const int row = nt * 16 + m;
                bf16x8 bfr = *(const bf16x8*)&w2t[row * 256 + half * 128 + (4 * j + g) * 8];
                acc2[0][nt] = __builtin_amdgcn_mfma_f32_16x16x32_bf16(aa[0], bfr, acc2[0][nt], 0, 0, 0);
                acc2[1][nt] = __builtin_amdgcn_mfma_f32_16x16x32_bf16(aa[1], bfr, acc2[1][nt], 0, 0, 0);
            }
        }
        if (half == 0) __syncthreads();  // H region reused by half 1
    }

    // ---- store with prefetched residual ----
#pragma unroll
    for (int mt = 0; mt < 2; ++mt)
#pragma unroll
        for (int nt = 0; nt < 4; ++nt)
#pragma unroll
            for (int rv = 0; rv < 4; ++rv) {
                const int row = (w + 4 * mt) * 16 + 4 * g + rv;
                const int col = nt * 16 + m;
                const size_t xi = base + (size_t)row * tmul + col;
                xout[xi] = xr[mt][nt][rv] + acc2[mt][nt][rv];
            }
}

extern "C" void kernel_launch(void* const* d_in, const int* in_sizes, int n_in,
                              void* d_out, int out_size, void* d_ws, size_t ws_size,
                              hipStream_t stream) {
    const float* v         = (const float*)d_in[0];
    const float* gamma_row = (const float*)d_in[1];
    const float* beta_row  = (const float*)d_in[2];
    const float* gamma_col = (const float*)d_in[3];
    const float* beta_col  = (const float*)d_in[4];
    const float* mp_row    = (const float*)d_in[5];
    const float* mm_row    = (const float*)d_in[6];
    const float* mp_col    = (const float*)d_in[7];
    const float* mm_col    = (const float*)d_in[8];
    const float* w1_row    = (const float*)d_in[9];
    const float* b1_row    = (const float*)d_in[10];
    const float* w2_row    = (const float*)d_in[11];
    const float* b2_row    = (const float*)d_in[12];
    const float* w1_col    = (const float*)d_in[13];
    const float* b1_col    = (const float*)d_in[14];
    const float* w2_col    = (const float*)d_in[15];
    const float* b2_col    = (const float*)d_in[16];
    const float* phi_row   = (const float*)d_in[17];
    const float* phi_col   = (const float*)d_in[18];
    float* out = (float*)d_out;
    char* ws   = (char*)d_ws;

    unsigned short* GfR  = (unsigned short*)ws;                      // 1 MB
    unsigned short* GfC  = (unsigned short*)(ws + (1u << 20));       // 1 MB
    unsigned short* w1tR = (unsigned short*)(ws + (2u << 20));
    unsigned short* w2tR = (unsigned short*)(ws + (2u << 20) + 32768);
    unsigned short* w1tC = (unsigned short*)(ws + (2u << 20) + 65536);
    unsigned short* w2tC = (unsigned short*)(ws + (2u << 20) + 98304);

    init_kernel<<<260, 256, 0, stream>>>(phi_row, mp_row, mm_row, GfR,
                                         phi_col, mp_col, mm_col, GfC,
                                         w1_row, w1_col, w2_row, w2_col,
                                         w1tR, w1tC, w2tR, w2tC);

    // row pass: seq=(b,h), rmul=8192 (h stride), tmul=64 (w stride)
    fused_kernel<<<512, 256, 0, stream>>>(v, out, GfR, w1tR, w2tR, b1_row, b2_row,
                                          gamma_row, beta_row, 8192, 64);
    // col pass: seq=(b,w), rmul=64 (w stride), tmul=8192 (h stride)
    fused_kernel<<<512, 256, 0, stream>>>(out, out, GfC, w1tC, w2tC, b1_col, b2_col,
                                          gamma_col, beta_col, 64, 8192);
}

// Round 14
// 128.106 us; speedup vs baseline: 1.3917x; 1.1242x over previous
//
#include <hip/hip_runtime.h>

typedef __attribute__((ext_vector_type(8))) short bf16x8;
typedef __attribute__((ext_vector_type(4))) float f32x4;

__device__ __forceinline__ float gelu_fast(float x) {
    const float u = 0.7978845608028654f * x * (1.0f + 0.044715f * x * x);
    return x * __builtin_amdgcn_rcpf(1.0f + __expf(-2.0f * u));
}

__device__ __forceinline__ unsigned short f2bf(float x) {
    union { float f; unsigned int u; } v; v.f = x;
    unsigned int r = v.u + 0x7FFF + ((v.u >> 16) & 1);
    return (unsigned short)(r >> 16);
}

// blocks [0,256): Gf production, parallel over (side, d-chunk, s-batch).
// blocks [256,260): weight transposes.
__global__ __launch_bounds__(256) void init_kernel(const float* __restrict__ phi_r, const float* __restrict__ mp_r,
                                                   const float* __restrict__ mm_r, unsigned short* __restrict__ GcR,
                                                   const float* __restrict__ phi_c, const float* __restrict__ mp_c,
                                                   const float* __restrict__ mm_c, unsigned short* __restrict__ GcC,
                                                   const float* __restrict__ w1r, const float* __restrict__ w1c,
                                                   const float* __restrict__ w2r, const float* __restrict__ w2c,
                                                   unsigned short* __restrict__ w1tr, unsigned short* __restrict__ w1tc,
                                                   unsigned short* __restrict__ w2tr, unsigned short* __restrict__ w2tc) {
    const int bid = blockIdx.x, tid = threadIdx.x;
    __shared__ float phis[256];
    __shared__ unsigned short tile[4096];  // 16 s x 256 (e-major, d-minor)
    if (bid < 256) {
        const int side = bid >> 7, rem = bid & 127;
        const int chunk = rem >> 3, s0 = (rem & 7) * 16;
        const float* phi = side ? phi_c : phi_r;
        const float* mp  = side ? mp_c  : mp_r;
        const float* mm  = side ? mm_c  : mm_r;
        unsigned short* Gct = side ? GcC : GcR;
        const int i = chunk * 256 + tid;
        float pe[16], po[16];
#pragma unroll
        for (int k = 0; k < 16; ++k) {
            const float a = mp[k * 4096 + i];
            const float b = mm[k * 4096 + i];
            pe[k] = a + b; po[k] = a - b;
        }
        phis[tid] = phi[s0 * 16 + tid];
        __syncthreads();
        const int e = tid & 63, dl = tid >> 6;
        const int d0 = chunk * 4;
        const int kk = d0 >> 5, g3 = (d0 >> 3) & 3, jl0 = d0 & 7;
#pragma unroll
        for (int sb = 0; sb < 16; ++sb) {
            const int s = s0 + sb;
            const float* pk = &phis[sb * 16];
            float acc = 0.0f;
            if (s & 1) {
#pragma unroll
                for (int k = 0; k < 16; ++k) acc += pk[k] * po[k];
            } else {
#pragma unroll
                for (int k = 0; k < 16; ++k) acc += pk[k] * pe[k];
            }
            tile[sb * 256 + e * 4 + dl] = f2bf(acc);
        }
        __syncthreads();
#pragma unroll
        for (int it = 0; it < 4; ++it) {
            const int p = it * 256 + tid;
            const int sb = p >> 6, ee = p & 63;
            uint2 v = *(const uint2*)&tile[sb * 256 + ee * 4];
            *(uint2*)&Gct[(size_t)(s0 + sb) * 4096 + (((ee >> 4) << 1) + kk) * 512 +
                          (g3 * 16 + (ee & 15)) * 8 + jl0] = v;
        }
    } else {
        const int b = bid - 256;
        if (b < 2) {
            const float* w1 = b ? w1c : w1r;
            unsigned short* dst = b ? w1tc : w1tr;
            const int n = tid;
            for (int k = 0; k < 64; ++k) dst[n * 64 + k] = f2bf(w1[k * 256 + n]);
        } else {
            const float* w2 = (b == 3) ? w2c : w2r;
            unsigned short* dst = (b == 3) ? w2tc : w2tr;
            const int n = tid & 63, kq = tid >> 6;
            for (int kk2 = 0; kk2 < 64; ++kk2) {
                const int k = kq * 64 + kk2;
                dst[n * 256 + k] = f2bf(w2[k * 64 + n]);
            }
        }
    }
}

// Fused pass: LN -> spec (reg-streaming B, double-buffered, no main-loop barriers)
// -> tree-reduce -> MLP(2 halves, residual prefetch at MLP start) -> store.
// 1 seq/block, 4 waves, grid 512 (2 blocks/CU). 50 KB LDS.
// REGISTER LEDGER (unified file, 2 waves/SIMD => 256/wave):
//   spec phase:  acc[8][4](128) + Ba/Bb(64) + misc(~60) = ~252  <- SATURATED, add NOTHING
//   reduction:   acc still live through T6                      <- add NOTHING (R13: xr here
//                                                                  spilled, +15 MB scratch)
//   MLP phase:   acc1(64)+acc2(32)+bw1(32)+misc(~40) = ~170     <- xr(32) fits HERE only
// __launch_bounds__ min-waves MUST stay 2 — (256,3) caps regs ~85, spills acc (R10).
// LDS byte regions (time-shared):
//   ys [0,18432) | scrA [18432,34816) scrB [34816,51200) | X [0,16384) | H [16384,49152)
#define SPEC_BODY(RR, BC, BN)                                                        \
    {                                                                                \
        const int s_ = 4 * (RR) + w;                                                 \
        if ((RR) < 31) {                                                             \
            const unsigned short* gq = Gf + (size_t)(s_ + 4) * 4096 + lane * 8;      \
            _Pragma("unroll")                                                        \
            for (int f = 0; f < 8; ++f) BN[f] = *(const bf16x8*)(gq + f * 512);      \
        }                                                                            \
        const int jmin_ = __builtin_amdgcn_readfirstlane(s_ >> 4);                   \
        _Pragma("unroll")                                                            \
        for (int j = 0; j < 8; ++j) {                                                \
            if (j >= jmin_) {                                                        \
                const int row_ = 16 + 16 * j - s_ + m;                               \
                const int c0_ = (g ^ (row_ & 7)) << 3;                               \
                const int ab_ = row_ * 64;                                           \
                bf16x8 a0_ = *(const bf16x8*)&lds[ab_ + c0_];                        \
                bf16x8 a1_ = *(const bf16x8*)&lds[ab_ + (c0_ ^ 32)];                 \
                _Pragma("unroll")                                                    \
                for (int nt = 0; nt < 4; ++nt) {                                     \
                    acc[j][nt] = __builtin_amdgcn_mfma_f32_16x16x32_bf16(a0_, BC[2 * nt], acc[j][nt], 0, 0, 0);     \
                    acc[j][nt] = __builtin_amdgcn_mfma_f32_16x16x32_bf16(a1_, BC[2 * nt + 1], acc[j][nt], 0, 0, 0); \
                }                                                                    \
            }                                                                        \
        }                                                                            \
    }

__global__ __launch_bounds__(256, 2) void fused_kernel(const float* __restrict__ xin,
                                                       float* __restrict__ xout,
                                                       const unsigned short* __restrict__ Gf,
                                                       const unsigned short* __restrict__ w1t,
                                                       const unsigned short* __restrict__ w2t,
                                                       const float* __restrict__ b1,
                                                       const float* __restrict__ b2,
                                                       const float* __restrict__ gamma,
                                                       const float* __restrict__ beta,
                                                       int rmul, int tmul) {
    __shared__ unsigned short lds[25600];  // 50 KB
    const int tid = threadIdx.x;
    const int w = tid >> 6, lane = tid & 63;
    const int seq = blockIdx.x;
    const int m = lane & 15, g = lane >> 4;
    const int bb = seq >> 7, rr = seq & 127;
    const size_t base = (size_t)bb * 1048576 + (size_t)rr * (size_t)rmul;

    // zero ys prefix rows 0..15 (bytes [0,2048))
    {
        uint2 z; z.x = 0u; z.y = 0u;
        *(uint2*)((char*)lds + tid * 8) = z;
    }

    // issue spec round-0 B load early (hides L2 latency under LN)
    bf16x8 Ba[8], Bb[8];
    {
        const unsigned short* gq = Gf + (size_t)w * 4096 + lane * 8;
#pragma unroll
        for (int f = 0; f < 8; ++f) Ba[f] = *(const bf16x8*)(gq + f * 512);
    }

    // ---- Phase 0: LayerNorm rows w*32 .. w*32+31 into swizzled ys ----
    {
        const float gl = gamma[lane], bl = beta[lane];
        float xv[32];
#pragma unroll
        for (int ti = 0; ti < 32; ++ti)
            xv[ti] = xin[base + (size_t)(w * 32 + ti) * tmul + lane];
#pragma unroll
        for (int ti = 0; ti < 32; ++ti) {
            const int t = w * 32 + ti;
            float s1 = xv[ti];
#pragma unroll
            for (int mm2 = 32; mm2 >= 1; mm2 >>= 1) s1 += __shfl_xor(s1, mm2);
            const float mu = s1 * (1.0f / 64.0f);
            const float dv = xv[ti] - mu;
            float s2 = dv * dv;
#pragma unroll
            for (int mm2 = 32; mm2 >= 1; mm2 >>= 1) s2 += __shfl_xor(s2, mm2);
            const float rstd = rsqrtf(s2 * (1.0f / 64.0f) + 1e-5f);
            const float nv = dv * rstd * gl + bl;
            lds[(t + 16) * 64 + (((lane >> 3) ^ (t & 7)) << 3) + (lane & 7)] = f2bf(nv);
        }
    }
    __syncthreads();  // ys complete

    // ---- Phase 1: spec main loop (no barriers) ----
    f32x4 acc[8][4];
#pragma unroll
    for (int j = 0; j < 8; ++j)
#pragma unroll
        for (int nt = 0; nt < 4; ++nt) {
            f32x4 z = {0.0f, 0.0f, 0.0f, 0.0f};
            acc[j][nt] = z;
        }
    for (int rp = 0; rp < 16; ++rp) {
        SPEC_BODY(2 * rp,     Ba, Bb);
        SPEC_BODY(2 * rp + 1, Bb, Ba);
    }

    // ---- Phase 2: pairwise tree reduction (32 KB scratch) ----
    char* const scrA = (char*)lds + 18432;
    char* const scrB = (char*)lds + 34816;
    // T1: w1 -> scrA (j0-3), w3 -> scrB (j0-3)
    if (w == 1 || w == 3) {
        char* pb = (w == 1 ? scrA : scrB) + lane * 16;
#pragma unroll
        for (int j = 0; j < 4; ++j)
#pragma unroll
            for (int nt = 0; nt < 4; ++nt)
                *(f32x4*)(pb + (j * 4 + nt) * 1024) = acc[j][nt];
    }
    // weight fragment loads (overlap reduction); wave owns hidden cols [32w,32w+32) per half
    bf16x8 bw1a[2][2], bw1b[2][2];
    float b1va[2], b1vb[2];
#pragma unroll
    for (int nt = 0; nt < 2; ++nt) {
        const int col0 = w * 32 + nt * 16 + m;
#pragma unroll
        for (int j = 0; j < 2; ++j) {
            bw1a[nt][j] = *(const bf16x8*)&w1t[col0 * 64 + (4 * j + g) * 8];
            bw1b[nt][j] = *(const bf16x8*)&w1t[(128 + col0) * 64 + (4 * j + g) * 8];
        }
        b1va[nt] = b1[col0];
        b1vb[nt] = b1[128 + col0];
    }
    __syncthreads();
    // T2: w0 += scrA, w2 += scrB (j0-3)
    if (w == 0 || w == 2) {
        const char* pb = (w == 0 ? scrA : scrB) + lane * 16;
#pragma unroll
        for (int j = 0; j < 4; ++j)
#pragma unroll
            for (int nt = 0; nt < 4; ++nt)
                acc[j][nt] += *(const f32x4*)(pb + (j * 4 + nt) * 1024);
    }
    __syncthreads();
    // T3: w1 -> scrA (j4-7), w3 -> scrB (j4-7)
    if (w == 1 || w == 3) {
        char* pb = (w == 1 ? scrA : scrB) + lane * 16;
#pragma unroll
        for (int j = 4; j < 8; ++j)
#pragma unroll
            for (int nt = 0; nt < 4; ++nt)
                *(f32x4*)(pb + ((j - 4) * 4 + nt) * 1024) = acc[j][nt];
    }
    __syncthreads();
    // T4: w0 += scrA, w2 += scrB (j4-7); then T5: w0 -> scrA (j4-7), w2 -> scrB (j0-3)
    if (w == 0 || w == 2) {
        const char* pb = (w == 0 ? scrA : scrB) + lane * 16;
#pragma unroll
        for (int j = 4; j < 8; ++j)
#pragma unroll
            for (int nt = 0; nt < 4; ++nt)
                acc[j][nt] += *(const f32x4*)(pb + ((j - 4) * 4 + nt) * 1024);
        if (w == 0) {
#pragma unroll
            for (int j = 4; j < 8; ++j)
#pragma unroll
                for (int nt = 0; nt < 4; ++nt)
                    *(f32x4*)(scrA + ((j - 4) * 4 + nt) * 1024 + lane * 16) = acc[j][nt];
        } else {
#pragma unroll
            for (int j = 0; j < 4; ++j)
#pragma unroll
                for (int nt = 0; nt < 4; ++nt)
                    *(f32x4*)(scrB + (j * 4 + nt) * 1024 + lane * 16) = acc[j][nt];
        }
    }
    __syncthreads();
    // T6: w0 finalizes j0-3 -> X rows 0..63; w2 finalizes j4-7 -> X rows 64..127
    if (w == 0) {
#pragma unroll
        for (int j = 0; j < 4; ++j)
#pragma unroll
            for (int nt = 0; nt < 4; ++nt) {
                acc[j][nt] += *(const f32x4*)(scrB + (j * 4 + nt) * 1024 + lane * 16);
#pragma unroll
                for (int rv = 0; rv < 4; ++rv) {
                    const int row = j * 16 + 4 * g + rv;
                    const int col = nt * 16 + m;
                    lds[row * 64 + (((col >> 3) ^ (row & 7)) << 3) + (col & 7)] = f2bf(acc[j][nt][rv]);
                }
            }
    } else if (w == 2) {
#pragma unroll
        for (int j = 4; j < 8; ++j)
#pragma unroll
            for (int nt = 0; nt < 4; ++nt) {
                acc[j][nt] += *(const f32x4*)(scrA + ((j - 4) * 4 + nt) * 1024 + lane * 16);
#pragma unroll
                for (int rv = 0; rv < 4; ++rv) {
                    const int row = j * 16 + 4 * g + rv;
                    const int col = nt * 16 + m;
                    lds[row * 64 + (((col >> 3) ^ (row & 7)) << 3) + (col & 7)] = f2bf(acc[j][nt][rv]);
                }
            }
    }
    __syncthreads();  // X complete; scratch dead; acc dead everywhere

    // ---- residual prefetch HERE (acc dead; MLP peak ~170+32 regs, fits) ----
    float xr[2][4][4];
#pragma unroll
    for (int mt = 0; mt < 2; ++mt)
#pragma unroll
        for (int nt = 0; nt < 4; ++nt)
#pragma unroll
            for (int rv = 0; rv < 4; ++rv)
                xr[mt][nt][rv] = xin[base + (size_t)((w + 4 * mt) * 16 + 4 * g + rv) * tmul + nt * 16 + m];

    // ---- Phase 3/4: MLP in two 128-col hidden halves; H at ush offset 8192, row stride 128 ush ----
    float b2v[4];
#pragma unroll
    for (int nt = 0; nt < 4; ++nt) b2v[nt] = b2[nt * 16 + m];
    f32x4 acc2[2][4];
#pragma unroll
    for (int mt = 0; mt < 2; ++mt)
#pragma unroll
        for (int nt = 0; nt < 4; ++nt) {
            f32x4 z = {b2v[nt], b2v[nt], b2v[nt], b2v[nt]};
            acc2[mt][nt] = z;
        }

#pragma unroll
    for (int half = 0; half < 2; ++half) {
        // GEMM1 half: H[:, 128*half + 32w .. +32) = gelu(X @ W1half + b1half)
        f32x4 acc1[8][2];
#pragma unroll
        for (int mt = 0; mt < 8; ++mt)
#pragma unroll
            for (int nt = 0; nt < 2; ++nt) {
                const float bv = half ? b1vb[nt] : b1va[nt];
                f32x4 z = {bv, bv, bv, bv};
                acc1[mt][nt] = z;
            }
#pragma unroll
        for (int mt = 0; mt < 8; ++mt) {
            const int row = mt * 16 + m;
            const int c0 = (g ^ (row & 7)) << 3;
            bf16x8 a0 = *(const bf16x8*)&lds[row * 64 + c0];
            bf16x8 a1 = *(const bf16x8*)&lds[row * 64 + (c0 ^ 32)];
#pragma unroll
            for (int nt = 0; nt < 2; ++nt) {
                const bf16x8 w0f = half ? bw1b[nt][0] : bw1a[nt][0];
                const bf16x8 w1f = half ? bw1b[nt][1] : bw1a[nt][1];
                acc1[mt][nt] = __builtin_amdgcn_mfma_f32_16x16x32_bf16(a0, w0f, acc1[mt][nt], 0, 0, 0);
                acc1[mt][nt] = __builtin_amdgcn_mfma_f32_16x16x32_bf16(a1, w1f, acc1[mt][nt], 0, 0, 0);
            }
        }
        // gelu + H half to LDS (cols within half: 32w + nt*16 + m)
#pragma unroll
        for (int mt = 0; mt < 8; ++mt)
#pragma unroll
            for (int nt = 0; nt < 2; ++nt) {
                const int col = w * 32 + nt * 16 + m;
                const int c = col >> 3, jj = col & 7;
#pragma unroll
                for (int rv = 0; rv < 4; ++rv) {
                    const int row = mt * 16 + 4 * g + rv;
                    lds[8192 + row * 128 + ((c ^ (row & 7)) << 3) + jj] = f2bf(gelu_fast(acc1[mt][nt][rv]));
                }
            }
        __syncthreads();  // H half complete

        // GEMM2 partial: K chunk [128*half, 128*half+128)
#pragma unroll
        for (int j = 0; j < 4; ++j) {
            bf16x8 aa[2];
#pragma unroll
            for (int mt = 0; mt < 2; ++mt) {
                const int row = (w + 4 * mt) * 16 + m;
                aa[mt] = *(const bf16x8*)&lds[8192 + row * 128 + (((4 * j + g) ^ (row & 7)) << 3)];
            }
#pragma unroll
            for (int nt = 0; nt < 4; ++nt) {
                const int row = nt * 16 + m;
                bf16x8 bfr = *(const bf16x8*)&w2t[row * 256 + half * 128 + (4 * j + g) * 8];
                acc2[0][nt] = __builtin_amdgcn_mfma_f32_16x16x32_bf16(aa[0], bfr, acc2[0][nt], 0, 0, 0);
                acc2[1][nt] = __builtin_amdgcn_mfma_f32_16x16x32_bf16(aa[1], bfr, acc2[1][nt], 0, 0, 0);
            }
        }
        if (half == 0) __syncthreads();  // H region reused by half 1
    }

    // ---- store with prefetched residual ----
#pragma unroll
    for (int mt = 0; mt < 2; ++mt)
#pragma unroll
        for (int nt = 0; nt < 4; ++nt)
#pragma unroll
            for (int rv = 0; rv < 4; ++rv) {
                const int row = (w + 4 * mt) * 16 + 4 * g + rv;
                const int col = nt * 16 + m;
                const size_t xi = base + (size_t)row * tmul + col;
                xout[xi] = xr[mt][nt][rv] + acc2[mt][nt][rv];
            }
}

extern "C" void kernel_launch(void* const* d_in, const int* in_sizes, int n_in,
                              void* d_out, int out_size, void* d_ws, size_t ws_size,
                              hipStream_t stream) {
    const float* v         = (const float*)d_in[0];
    const float* gamma_row = (const float*)d_in[1];
    const float* beta_row  = (const float*)d_in[2];
    const float* gamma_col = (const float*)d_in[3];
    const float* beta_col  = (const float*)d_in[4];
    const float* mp_row    = (const float*)d_in[5];
    const float* mm_row    = (const float*)d_in[6];
    const float* mp_col    = (const float*)d_in[7];
    const float* mm_col    = (const float*)d_in[8];
    const float* w1_row    = (const float*)d_in[9];
    const float* b1_row    = (const float*)d_in[10];
    const float* w2_row    = (const float*)d_in[11];
    const float* b2_row    = (const float*)d_in[12];
    const float* w1_col    = (const float*)d_in[13];
    const float* b1_col    = (const float*)d_in[14];
    const float* w2_col    = (const float*)d_in[15];
    const float* b2_col    = (const float*)d_in[16];
    const float* phi_row   = (const float*)d_in[17];
    const float* phi_col   = (const float*)d_in[18];
    float* out = (float*)d_out;
    char* ws   = (char*)d_ws;

    unsigned short* GfR  = (unsigned short*)ws;                      // 1 MB
    unsigned short* GfC  = (unsigned short*)(ws + (1u << 20));       // 1 MB
    unsigned short* w1tR = (unsigned short*)(ws + (2u << 20));
    unsigned short* w2tR = (unsigned short*)(ws + (2u << 20) + 32768);
    unsigned short* w1tC = (unsigned short*)(ws + (2u << 20) + 65536);
    unsigned short* w2tC = (unsigned short*)(ws + (2u << 20) + 98304);

    init_kernel<<<260, 256, 0, stream>>>(phi_row, mp_row, mm_row, GfR,
                                         phi_col, mp_col, mm_col, GfC,
                                         w1_row, w1_col, w2_row, w2_col,
                                         w1tR, w1tC, w2tR, w2tC);

    // row pass: seq=(b,h), rmul=8192 (h stride), tmul=64 (w stride)
    fused_kernel<<<512, 256, 0, stream>>>(v, out, GfR, w1tR, w2tR, b1_row, b2_row,
                                          gamma_row, beta_row, 8192, 64);
    // col pass: seq=(b,w), rmul=64 (w stride), tmul=8192 (h stride)
    fused_kernel<<<512, 256, 0, stream>>>(out, out, GfC, w1tC, w2tC, b1_col, b2_col,
                                          gamma_col, beta_col, 64, 8192);
}